// Round 11
// baseline (223.818 us; speedup 1.0000x reference)
//
#include <hip/hip_runtime.h>
#include <hip/hip_bf16.h>

// ---- problem constants ----
#define BATCH 2
#define SEQ   2048
#define EMB   1024
#define NHEAD 16
#define HDIM  64
#define MTOT  (BATCH*SEQ)     // 4096
#define KTOT  EMB             // 1024

#define NX  (MTOT*EMB)        // 4,194,304  X elems
#define NW1 (3*EMB*EMB)       // 3,145,728  Wqkv elems
#define NW2 (EMB*EMB)         // 1,048,576  Wout elems
#define NOUT (MTOT*EMB)       // 4,194,304  out elems (fp32, bias-init)
#define NCVT (NX+NW1+NW2)

typedef short bf8 __attribute__((ext_vector_type(8)));   // 8 bf16 (4 VGPRs) MFMA A/B frag
typedef short s4v __attribute__((ext_vector_type(4)));   // 4 bf16, 8B
typedef float f4  __attribute__((ext_vector_type(4)));   // MFMA C/D frag
typedef unsigned int uint;

__device__ __forceinline__ short f2b(float f) {
    __hip_bfloat16 h = __float2bfloat16(f);
    return __builtin_bit_cast(short, h);
}
// async global->LDS, 16B per lane; lds dest = wave-uniform base + lane*16
__device__ __forceinline__ void gl_lds16(const short* g, short* l) {
    __builtin_amdgcn_global_load_lds(
        (const __attribute__((address_space(1))) uint*)g,
        (__attribute__((address_space(3))) uint*)l, 16, 0, 0);
}
// 64B-row LDS tiles: bank swizzle (store global chunk c^f(r) at LDS chunk c).
#define SWZ_SRC(lane)      ((((lane) ^ ((lane)>>2) ^ ((lane)>>4)) & 3) * 8)
#define SWZ_RD(quad, l16)  ((((quad) ^ (l16) ^ ((l16)>>2)) & 3) * 8)

// ============================================================================
// Kernel 0: fp32 -> bf16 convert (X, Wqkv, Wout) + bias-init of out (fp32).
// out-init is re-done on EVERY call (harness re-poisons d_out).
// ============================================================================
__global__ __launch_bounds__(256) void cvt_all(
    const float* __restrict__ X, const float* __restrict__ W1,
    const float* __restrict__ W2, const float* __restrict__ Bout,
    short* __restrict__ xb, short* __restrict__ w1b, short* __restrict__ w2b,
    float* __restrict__ out)
{
    int i4 = (blockIdx.x * 256 + threadIdx.x) * 4;
    if (i4 < NCVT) {
        const float* src; short* dst; int off;
        if (i4 < NX)            { src = X;  dst = xb;  off = i4; }
        else if (i4 < NX + NW1) { src = W1; dst = w1b; off = i4 - NX; }
        else                    { src = W2; dst = w2b; off = i4 - NX - NW1; }
        float4 v = *(const float4*)&src[off];
        s4v o; o[0]=f2b(v.x); o[1]=f2b(v.y); o[2]=f2b(v.z); o[3]=f2b(v.w);
        *(s4v*)&dst[off] = o;
    } else {
        int off = i4 - NCVT;                 // 0..NOUT-1
        float4 bv = *(const float4*)&Bout[off & (EMB - 1)];
        *(float4*)&out[off] = bv;
    }
}

// ============================================================================
// Kernel 1: QKV projection. 128x64 tile, BK=64, single-buffer DMA staging.
// Grid 32x48 = 1536 blocks -> 6 blocks/CU (R10's 768 capped us at 3/CU; no
// pipe was saturated -> more TLP to overlap barrier drains). 24KB LDS.
// XOR bank swizzle. Scatter epilogue: Q,K [B,H,S,D]; V^T key-swizzled.
// ============================================================================
__global__ __launch_bounds__(256) void gemm_qkv(
    const short* __restrict__ Xb, const short* __restrict__ Wb,
    const float* __restrict__ bias,
    short* __restrict__ qb, short* __restrict__ kb, short* __restrict__ vtb)
{
    __shared__ __align__(16) short As[2*128*32];   // 16KB [kc][row][32sh]
    __shared__ __align__(16) short Bs[2*64*32];    //  8KB [kc][row][32sh]
    const int tid  = threadIdx.x;
    const int lane = tid & 63;
    const int w    = tid >> 6;
    const int l16  = lane & 15, quad = lane >> 4;
    const int wm   = (w >> 1) * 64, wn = (w & 1) * 32;
    const int srow = (lane >> 2);
    const int scol = SWZ_SRC(lane);
    f4 acc[4][2] = {};
    for (int k0 = 0; k0 < KTOT; k0 += 64) {
        #pragma unroll
        for (int t = 0; t < 4; t++) {              // A: 4 DMA/wave
            const int rr = w*32 + (t & 1)*16;
            const int kc = t >> 1;
            int ra = blockIdx.x*128 + rr + srow;
            gl_lds16(&Xb[(size_t)ra*KTOT + k0 + kc*32 + scol], &As[kc*4096 + rr*32]);
        }
        #pragma unroll
        for (int kc = 0; kc < 2; kc++) {           // B: 2 DMA/wave
            int rb = blockIdx.y*64 + w*16 + srow;
            gl_lds16(&Wb[(size_t)rb*KTOT + k0 + kc*32 + scol], &Bs[kc*2048 + (w*16)*32]);
        }
        __syncthreads();
        #pragma unroll
        for (int kc = 0; kc < 2; kc++) {
            bf8 af[4], bf[2];
            #pragma unroll
            for (int t = 0; t < 4; t++)
                af[t] = *(const bf8*)&As[kc*4096 + (wm + t*16 + l16)*32 + SWZ_RD(quad, l16)];
            #pragma unroll
            for (int t = 0; t < 2; t++)
                bf[t] = *(const bf8*)&Bs[kc*2048 + (wn + t*16 + l16)*32 + SWZ_RD(quad, l16)];
            #pragma unroll
            for (int mt = 0; mt < 4; mt++)
                #pragma unroll
                for (int nt = 0; nt < 2; nt++)
                    acc[mt][nt] = __builtin_amdgcn_mfma_f32_16x16x32_bf16(af[mt], bf[nt], acc[mt][nt], 0, 0, 0);
        }
        __syncthreads();
    }
    #pragma unroll
    for (int mt = 0; mt < 4; mt++)
    #pragma unroll
    for (int nt = 0; nt < 2; nt++) {
        int colg = blockIdx.y*64 + wn + nt*16 + l16;
        float bv = bias[colg];
        #pragma unroll
        for (int r = 0; r < 4; r++) {
            int rowg = blockIdx.x*128 + wm + mt*16 + quad*4 + r;
            short h = f2b(acc[mt][nt][r] + bv);
            int bb = rowg >> 11, s = rowg & 2047;
            if (colg < 1024) {
                int hh = colg >> 6, d = colg & 63;
                qb[(((bb*NHEAD + hh)*SEQ + s) << 6) + d] = h;
            } else if (colg < 2048) {
                int c2 = colg - 1024, hh = c2 >> 6, d = c2 & 63;
                kb[(((bb*NHEAD + hh)*SEQ + s) << 6) + d] = h;
            } else {
                int c3 = colg - 2048, hh = c3 >> 6, d = c3 & 63;
                int ssw = (s & ~63) | (((s & 15) << 2) | ((s >> 4) & 3));
                vtb[((bb*NHEAD + hh)*HDIM + d)*SEQ + ssw] = h;
            }
        }
    }
}

// ============================================================================
// Kernel 2: causal flash attention (unchanged from R10). Balanced map: CU
// slot gets 4 tiles of the SAME head, tq in {j,15-j,16+j,31-j}. LDS K/V dbuf
// DMA; masked stage peeled; no-max softmax; exp2; v_perm pack.
// ============================================================================
__global__ __launch_bounds__(256, 4) void attn(
    const short* __restrict__ qb, const short* __restrict__ kb,
    const short* __restrict__ vtb, short* __restrict__ ctx)
{
    __shared__ __align__(16) short Ks[2*4096];      // 16KB [buf][c][key][32sh]
    __shared__ __align__(16) short Vs[2*4096];      // 16KB
    __shared__ __align__(16) short pl[4][16*64];    //  8KB
    const int tid = threadIdx.x;
    const int w = tid >> 6, lane = tid & 63;
    const int l16 = lane & 15, quad = lane >> 4;
    const int f  = blockIdx.x;                      // 0..1023
    const int bh = f & 31;
    const int j5 = (f >> 5) & 7;
    const int hq = f >> 8;                          // 0..3
    const int tq = (hq == 0) ? j5 : (hq == 1) ? (15 - j5)
                 : (hq == 2) ? (16 + j5) : (31 - j5);
    const int q0w = tq*64 + w*16;
    const int base = bh * (SEQ*HDIM);
    short* myp = pl[w];
    const float SC = 0.125f * 1.44269504f;          // 1/sqrt(64) * log2(e)

    const int lq  = lane >> 2;
    const int lsw = SWZ_SRC(lane);

    const bool isk = (w < 2);
    short* tb = isk ? Ks : Vs;
    const int sstep = isk ? 64*HDIM : 64;
    const short* sp0; const short* sp1; const short* sp2; const short* sp3;
    int dof[4];
    {
        const int wb2 = (w & 1) * 4;
        #pragma unroll
        for (int tt = 0; tt < 4; tt++) {
            int t = wb2 + tt, cc = t & 1, g = (t >> 1) & 3;
            dof[tt] = (cc*64 + g*16)*32;
            const short* s = isk ? &kb[base + (g*16 + lq)*HDIM + cc*32 + lsw]
                                 : &vtb[base + (g*16 + lq)*SEQ + cc*32 + lsw];
            if (tt == 0) sp0 = s; else if (tt == 1) sp1 = s;
            else if (tt == 2) sp2 = s; else sp3 = s;
        }
    }

    bf8 qa[2];
    #pragma unroll
    for (int kc = 0; kc < 2; kc++)
        qa[kc] = *(const bf8*)&qb[base + (q0w + l16)*HDIM + kc*32 + quad*8];

    f4 o[4] = {};
    float lacc[4] = {};
    const int rdK = l16*32 + SWZ_RD(quad, l16);

    gl_lds16(sp0, tb + dof[0]); gl_lds16(sp1, tb + dof[1]);
    gl_lds16(sp2, tb + dof[2]); gl_lds16(sp3, tb + dof[3]);
    sp0 += sstep; sp1 += sstep; sp2 += sstep; sp3 += sstep;
    __syncthreads();

    int buf = 0;
    for (int st = 0; st <= tq; st++) {
        if (st < tq) {
            short* d = tb + (buf ^ 1)*4096;
            gl_lds16(sp0, d + dof[0]); gl_lds16(sp1, d + dof[1]);
            gl_lds16(sp2, d + dof[2]); gl_lds16(sp3, d + dof[3]);
            sp0 += sstep; sp1 += sstep; sp2 += sstep; sp3 += sstep;
        }
        const int kbase = buf*4096 + rdK;
        f4 s[4] = {};
        #pragma unroll
        for (int kf = 0; kf < 4; kf++)
            #pragma unroll
            for (int c = 0; c < 2; c++) {
                bf8 kfr = *(const bf8*)&Ks[kbase + (c*64 + kf*16)*32];
                s[kf] = __builtin_amdgcn_mfma_f32_16x16x32_bf16(qa[c], kfr, s[kf], 0, 0, 0);
            }
        if (st == tq) {
            const int j0 = st*64;
            #pragma unroll
            for (int r = 0; r < 4; r++) {
                const int row = quad*4 + r;
                const int qi  = q0w + row;
                float e[4];
                #pragma unroll
                for (int kf = 0; kf < 4; kf++) {
                    e[kf] = __builtin_amdgcn_exp2f(s[kf][r] * SC);
                    if (j0 + kf*16 + l16 > qi) e[kf] = 0.0f;
                    lacc[r] += e[kf];
                }
                uint u01 = __builtin_amdgcn_perm(__builtin_bit_cast(uint, e[1]),
                                                 __builtin_bit_cast(uint, e[0]), 0x07060302u);
                uint u23 = __builtin_amdgcn_perm(__builtin_bit_cast(uint, e[3]),
                                                 __builtin_bit_cast(uint, e[2]), 0x07060302u);
                uint2 pk = {u01, u23};
                int c8 = ((l16 >> 1) ^ (row & 7));
                *(uint2*)&myp[row*64 + c8*8 + (l16 & 1)*4] = pk;
            }
        } else {
            #pragma unroll
            for (int r = 0; r < 4; r++) {
                const int row = quad*4 + r;
                float e[4];
                #pragma unroll
                for (int kf = 0; kf < 4; kf++) {
                    e[kf] = __builtin_amdgcn_exp2f(s[kf][r] * SC);
                    lacc[r] += e[kf];
                }
                uint u01 = __builtin_amdgcn_perm(__builtin_bit_cast(uint, e[1]),
                                                 __builtin_bit_cast(uint, e[0]), 0x07060302u);
                uint u23 = __builtin_amdgcn_perm(__builtin_bit_cast(uint, e[3]),
                                                 __builtin_bit_cast(uint, e[2]), 0x07060302u);
                uint2 pk = {u01, u23};
                int c8 = ((l16 >> 1) ^ (row & 7));
                *(uint2*)&myp[row*64 + c8*8 + (l16 & 1)*4] = pk;
            }
        }
        asm volatile("" ::: "memory");
        bf8 pa[2];
        #pragma unroll
        for (int kc = 0; kc < 2; kc++)
            pa[kc] = *(const bf8*)&myp[l16*64 + (((kc*4 + quad) ^ (l16 & 7)))*8];
        #pragma unroll
        for (int dt = 0; dt < 4; dt++)
            #pragma unroll
            for (int c = 0; c < 2; c++) {
                bf8 vf = *(const bf8*)&Vs[kbase + (c*64 + dt*16)*32];
                o[dt] = __builtin_amdgcn_mfma_f32_16x16x32_bf16(pa[c], vf, o[dt], 0, 0, 0);
            }
        __syncthreads();
        buf ^= 1;
    }
    #pragma unroll
    for (int r = 0; r < 4; r++) {
        float v = lacc[r];
        v += __shfl_xor(v, 1);
        v += __shfl_xor(v, 2);
        v += __shfl_xor(v, 4);
        v += __shfl_xor(v, 8);
        lacc[r] = v;
    }
    const int b = bh >> 4, h = bh & 15;
    #pragma unroll
    for (int r = 0; r < 4; r++) {
        float inv = 1.0f / lacc[r];
        int qi = q0w + quad*4 + r;
        int rowoff = (b*SEQ + qi)*EMB + h*HDIM;
        #pragma unroll
        for (int dt = 0; dt < 4; dt++)
            ctx[rowoff + dt*16 + l16] = f2b(o[dt][r] * inv);
    }
}

// ============================================================================
// Kernel 3: output projection, SPLIT-K=4. 256 tiles x 4 K-slices = 1024
// blocks (4/CU TLP). Each block: 128x128 tile, 4 iters of BK=64. Epilogue:
// HW fp32 atomic add into bias-pre-initialized out (cvt_all).
// ============================================================================
__global__ __launch_bounds__(256) void gemm_out(
    const short* __restrict__ A, const short* __restrict__ Wb,
    float* __restrict__ out)
{
    __shared__ __align__(16) short As[2*128*32];   // 16KB
    __shared__ __align__(16) short Bs[2*128*32];   // 16KB
    const int f  = blockIdx.x;                     // 0..1023
    const int ks = f & 3;                          // K slice
    const int t  = f >> 2;                         // 0..255
    const int bx = t & 31, by = t >> 5;            // 32 x 8 tiles
    const int tid  = threadIdx.x;
    const int lane = tid & 63;
    const int w    = tid >> 6;
    const int l16  = lane & 15, quad = lane >> 4;
    const int wm   = (w >> 1) * 64, wn = (w & 1) * 64;
    const int srow = (lane >> 2);
    const int scol = SWZ_SRC(lane);
    f4 acc[4][4] = {};
    const int kbeg = ks * 256, kend = kbeg + 256;
    for (int k0 = kbeg; k0 < kend; k0 += 64) {
        #pragma unroll
        for (int t2 = 0; t2 < 4; t2++) {
            const int rr = w*32 + (t2 & 1)*16;
            const int kc = t2 >> 1;
            int ra = bx*128 + rr + srow;
            gl_lds16(&A[(size_t)ra*KTOT + k0 + kc*32 + scol],  &As[kc*4096 + rr*32]);
            int rb = by*128 + rr + srow;
            gl_lds16(&Wb[(size_t)rb*KTOT + k0 + kc*32 + scol], &Bs[kc*4096 + rr*32]);
        }
        __syncthreads();
        #pragma unroll
        for (int kc = 0; kc < 2; kc++) {
            bf8 af[4], bf[4];
            #pragma unroll
            for (int i = 0; i < 4; i++) {
                af[i] = *(const bf8*)&As[kc*4096 + (wm + i*16 + l16)*32 + SWZ_RD(quad, l16)];
                bf[i] = *(const bf8*)&Bs[kc*4096 + (wn + i*16 + l16)*32 + SWZ_RD(quad, l16)];
            }
            #pragma unroll
            for (int mt = 0; mt < 4; mt++)
                #pragma unroll
                for (int nt = 0; nt < 4; nt++)
                    acc[mt][nt] = __builtin_amdgcn_mfma_f32_16x16x32_bf16(af[mt], bf[nt], acc[mt][nt], 0, 0, 0);
        }
        __syncthreads();
    }
    #pragma unroll
    for (int mt = 0; mt < 4; mt++)
    #pragma unroll
    for (int nt = 0; nt < 4; nt++) {
        int colg = by*128 + wn + nt*16 + l16;
        #pragma unroll
        for (int r = 0; r < 4; r++) {
            int rowg = bx*128 + wm + mt*16 + quad*4 + r;
            unsafeAtomicAdd(&out[(size_t)rowg*EMB + colg], acc[mt][nt][r]);
        }
    }
}

extern "C" void kernel_launch(void* const* d_in, const int* in_sizes, int n_in,
                              void* d_out, int out_size, void* d_ws, size_t ws_size,
                              hipStream_t stream) {
    const float* X    = (const float*)d_in[0];   // [B,S,E] fp32
    const float* Wqkv = (const float*)d_in[1];   // [3E,E]  fp32
    const float* Bqkv = (const float*)d_in[2];   // [3E]    fp32
    const float* Wout = (const float*)d_in[3];   // [E,E]   fp32
    const float* Bout = (const float*)d_in[4];   // [E]     fp32
    float* out = (float*)d_out;                  // [B,S,E] fp32

    short* xb    = (short*)d_ws;                 // bf16 X      (8 MB)
    short* w1b   = xb  + NX;                     // bf16 Wqkv   (6 MB)
    short* w2b   = w1b + NW1;                    // bf16 Wout   (2 MB)
    short* qb    = w2b + NW2;
    short* kb    = qb  + NX;
    short* vtb   = kb  + NX;
    short* ctx   = vtb + NX;                     // total 48 MB

    cvt_all<<<(NCVT + NOUT)/1024, 256, 0, stream>>>(X, Wqkv, Wout, Bout,
                                                    xb, w1b, w2b, out);
    dim3 g1(MTOT/128, 3*EMB/64);                 // 32 x 48
    gemm_qkv<<<g1, 256, 0, stream>>>(xb, w1b, Bqkv, qb, kb, vtb);
    attn<<<dim3(1024), 256, 0, stream>>>(qb, kb, vtb, ctx);
    gemm_out<<<dim3(1024), 256, 0, stream>>>(ctx, w2b, out);
}

// Round 12
// 184.312 us; speedup vs baseline: 1.2143x; 1.2143x over previous
//
#include <hip/hip_runtime.h>
#include <hip/hip_bf16.h>

// ---- problem constants ----
#define BATCH 2
#define SEQ   2048
#define EMB   1024
#define NHEAD 16
#define HDIM  64
#define MTOT  (BATCH*SEQ)     // 4096
#define KTOT  EMB             // 1024

#define NX  (MTOT*EMB)        // 4,194,304  X elems
#define NW1 (3*EMB*EMB)       // 3,145,728  Wqkv elems
#define NW2 (EMB*EMB)         // 1,048,576  Wout elems
#define NCVT (NX+NW1+NW2)

typedef short bf8 __attribute__((ext_vector_type(8)));   // 8 bf16 (4 VGPRs) MFMA A/B frag
typedef short s4v __attribute__((ext_vector_type(4)));   // 4 bf16, 8B
typedef float f4  __attribute__((ext_vector_type(4)));   // MFMA C/D frag
typedef unsigned int uint;

__device__ __forceinline__ short f2b(float f) {
    __hip_bfloat16 h = __float2bfloat16(f);
    return __builtin_bit_cast(short, h);
}
// async global->LDS, 16B per lane; lds dest = wave-uniform base + lane*16
__device__ __forceinline__ void gl_lds16(const short* g, short* l) {
    __builtin_amdgcn_global_load_lds(
        (const __attribute__((address_space(1))) uint*)g,
        (__attribute__((address_space(3))) uint*)l, 16, 0, 0);
}
// 64B-row LDS tiles: bank swizzle (store global chunk c^f(r) at LDS chunk c).
#define SWZ_SRC(lane)      ((((lane) ^ ((lane)>>2) ^ ((lane)>>4)) & 3) * 8)
#define SWZ_RD(quad, l16)  ((((quad) ^ (l16) ^ ((l16)>>2)) & 3) * 8)

// ============================================================================
// Kernel 0: fp32 -> bf16 convert (X, Wqkv, Wout). Coalesced float4 -> bf16x4.
// ============================================================================
__global__ __launch_bounds__(256) void cvt_all(
    const float* __restrict__ X, const float* __restrict__ W1,
    const float* __restrict__ W2,
    short* __restrict__ xb, short* __restrict__ w1b, short* __restrict__ w2b)
{
    int i4 = (blockIdx.x * 256 + threadIdx.x) * 4;
    const float* src; short* dst; int off;
    if (i4 < NX)            { src = X;  dst = xb;  off = i4; }
    else if (i4 < NX + NW1) { src = W1; dst = w1b; off = i4 - NX; }
    else                    { src = W2; dst = w2b; off = i4 - NX - NW1; }
    float4 v = *(const float4*)&src[off];
    s4v o; o[0]=f2b(v.x); o[1]=f2b(v.y); o[2]=f2b(v.z); o[3]=f2b(v.w);
    *(s4v*)&dst[off] = o;
}

// ============================================================================
// Kernel 1: QKV projection (R11 structure, kept). 128x64 tile, BK=64,
// single-buffer DMA staging, grid 32x48 = 1536 blocks -> 6 blocks/CU.
// XOR bank swizzle. Scatter epilogue: Q,K [B,H,S,D]; V^T key-swizzled.
// ============================================================================
__global__ __launch_bounds__(256) void gemm_qkv(
    const short* __restrict__ Xb, const short* __restrict__ Wb,
    const float* __restrict__ bias,
    short* __restrict__ qb, short* __restrict__ kb, short* __restrict__ vtb)
{
    __shared__ __align__(16) short As[2*128*32];   // 16KB [kc][row][32sh]
    __shared__ __align__(16) short Bs[2*64*32];    //  8KB [kc][row][32sh]
    const int tid  = threadIdx.x;
    const int lane = tid & 63;
    const int w    = tid >> 6;
    const int l16  = lane & 15, quad = lane >> 4;
    const int wm   = (w >> 1) * 64, wn = (w & 1) * 32;
    const int srow = (lane >> 2);
    const int scol = SWZ_SRC(lane);
    f4 acc[4][2] = {};
    for (int k0 = 0; k0 < KTOT; k0 += 64) {
        #pragma unroll
        for (int t = 0; t < 4; t++) {              // A: 4 DMA/wave
            const int rr = w*32 + (t & 1)*16;
            const int kc = t >> 1;
            int ra = blockIdx.x*128 + rr + srow;
            gl_lds16(&Xb[(size_t)ra*KTOT + k0 + kc*32 + scol], &As[kc*4096 + rr*32]);
        }
        #pragma unroll
        for (int kc = 0; kc < 2; kc++) {           // B: 2 DMA/wave
            int rb = blockIdx.y*64 + w*16 + srow;
            gl_lds16(&Wb[(size_t)rb*KTOT + k0 + kc*32 + scol], &Bs[kc*2048 + (w*16)*32]);
        }
        __syncthreads();
        #pragma unroll
        for (int kc = 0; kc < 2; kc++) {
            bf8 af[4], bf[2];
            #pragma unroll
            for (int t = 0; t < 4; t++)
                af[t] = *(const bf8*)&As[kc*4096 + (wm + t*16 + l16)*32 + SWZ_RD(quad, l16)];
            #pragma unroll
            for (int t = 0; t < 2; t++)
                bf[t] = *(const bf8*)&Bs[kc*2048 + (wn + t*16 + l16)*32 + SWZ_RD(quad, l16)];
            #pragma unroll
            for (int mt = 0; mt < 4; mt++)
                #pragma unroll
                for (int nt = 0; nt < 2; nt++)
                    acc[mt][nt] = __builtin_amdgcn_mfma_f32_16x16x32_bf16(af[mt], bf[nt], acc[mt][nt], 0, 0, 0);
        }
        __syncthreads();
    }
    #pragma unroll
    for (int mt = 0; mt < 4; mt++)
    #pragma unroll
    for (int nt = 0; nt < 2; nt++) {
        int colg = blockIdx.y*64 + wn + nt*16 + l16;
        float bv = bias[colg];
        #pragma unroll
        for (int r = 0; r < 4; r++) {
            int rowg = blockIdx.x*128 + wm + mt*16 + quad*4 + r;
            short h = f2b(acc[mt][nt][r] + bv);
            int bb = rowg >> 11, s = rowg & 2047;
            if (colg < 1024) {
                int hh = colg >> 6, d = colg & 63;
                qb[(((bb*NHEAD + hh)*SEQ + s) << 6) + d] = h;
            } else if (colg < 2048) {
                int c2 = colg - 1024, hh = c2 >> 6, d = c2 & 63;
                kb[(((bb*NHEAD + hh)*SEQ + s) << 6) + d] = h;
            } else {
                int c3 = colg - 2048, hh = c3 >> 6, d = c3 & 63;
                int ssw = (s & ~63) | (((s & 15) << 2) | ((s >> 4) & 3));
                vtb[((bb*NHEAD + hh)*HDIM + d)*SEQ + ssw] = h;
            }
        }
    }
}

// ============================================================================
// Kernel 2: causal flash attention (unchanged from R10). Balanced map: CU
// slot gets 4 tiles of the SAME head, tq in {j,15-j,16+j,31-j}. LDS K/V dbuf
// DMA; masked stage peeled; no-max softmax; exp2; v_perm pack.
// ============================================================================
__global__ __launch_bounds__(256, 4) void attn(
    const short* __restrict__ qb, const short* __restrict__ kb,
    const short* __restrict__ vtb, short* __restrict__ ctx)
{
    __shared__ __align__(16) short Ks[2*4096];      // 16KB [buf][c][key][32sh]
    __shared__ __align__(16) short Vs[2*4096];      // 16KB
    __shared__ __align__(16) short pl[4][16*64];    //  8KB
    const int tid = threadIdx.x;
    const int w = tid >> 6, lane = tid & 63;
    const int l16 = lane & 15, quad = lane >> 4;
    const int f  = blockIdx.x;                      // 0..1023
    const int bh = f & 31;
    const int j5 = (f >> 5) & 7;
    const int hq = f >> 8;                          // 0..3
    const int tq = (hq == 0) ? j5 : (hq == 1) ? (15 - j5)
                 : (hq == 2) ? (16 + j5) : (31 - j5);
    const int q0w = tq*64 + w*16;
    const int base = bh * (SEQ*HDIM);
    short* myp = pl[w];
    const float SC = 0.125f * 1.44269504f;          // 1/sqrt(64) * log2(e)

    const int lq  = lane >> 2;
    const int lsw = SWZ_SRC(lane);

    const bool isk = (w < 2);
    short* tb = isk ? Ks : Vs;
    const int sstep = isk ? 64*HDIM : 64;
    const short* sp0; const short* sp1; const short* sp2; const short* sp3;
    int dof[4];
    {
        const int wb2 = (w & 1) * 4;
        #pragma unroll
        for (int tt = 0; tt < 4; tt++) {
            int t = wb2 + tt, cc = t & 1, g = (t >> 1) & 3;
            dof[tt] = (cc*64 + g*16)*32;
            const short* s = isk ? &kb[base + (g*16 + lq)*HDIM + cc*32 + lsw]
                                 : &vtb[base + (g*16 + lq)*SEQ + cc*32 + lsw];
            if (tt == 0) sp0 = s; else if (tt == 1) sp1 = s;
            else if (tt == 2) sp2 = s; else sp3 = s;
        }
    }

    bf8 qa[2];
    #pragma unroll
    for (int kc = 0; kc < 2; kc++)
        qa[kc] = *(const bf8*)&qb[base + (q0w + l16)*HDIM + kc*32 + quad*8];

    f4 o[4] = {};
    float lacc[4] = {};
    const int rdK = l16*32 + SWZ_RD(quad, l16);

    gl_lds16(sp0, tb + dof[0]); gl_lds16(sp1, tb + dof[1]);
    gl_lds16(sp2, tb + dof[2]); gl_lds16(sp3, tb + dof[3]);
    sp0 += sstep; sp1 += sstep; sp2 += sstep; sp3 += sstep;
    __syncthreads();

    int buf = 0;
    for (int st = 0; st <= tq; st++) {
        if (st < tq) {
            short* d = tb + (buf ^ 1)*4096;
            gl_lds16(sp0, d + dof[0]); gl_lds16(sp1, d + dof[1]);
            gl_lds16(sp2, d + dof[2]); gl_lds16(sp3, d + dof[3]);
            sp0 += sstep; sp1 += sstep; sp2 += sstep; sp3 += sstep;
        }
        const int kbase = buf*4096 + rdK;
        f4 s[4] = {};
        #pragma unroll
        for (int kf = 0; kf < 4; kf++)
            #pragma unroll
            for (int c = 0; c < 2; c++) {
                bf8 kfr = *(const bf8*)&Ks[kbase + (c*64 + kf*16)*32];
                s[kf] = __builtin_amdgcn_mfma_f32_16x16x32_bf16(qa[c], kfr, s[kf], 0, 0, 0);
            }
        if (st == tq) {
            const int j0 = st*64;
            #pragma unroll
            for (int r = 0; r < 4; r++) {
                const int row = quad*4 + r;
                const int qi  = q0w + row;
                float e[4];
                #pragma unroll
                for (int kf = 0; kf < 4; kf++) {
                    e[kf] = __builtin_amdgcn_exp2f(s[kf][r] * SC);
                    if (j0 + kf*16 + l16 > qi) e[kf] = 0.0f;
                    lacc[r] += e[kf];
                }
                uint u01 = __builtin_amdgcn_perm(__builtin_bit_cast(uint, e[1]),
                                                 __builtin_bit_cast(uint, e[0]), 0x07060302u);
                uint u23 = __builtin_amdgcn_perm(__builtin_bit_cast(uint, e[3]),
                                                 __builtin_bit_cast(uint, e[2]), 0x07060302u);
                uint2 pk = {u01, u23};
                int c8 = ((l16 >> 1) ^ (row & 7));
                *(uint2*)&myp[row*64 + c8*8 + (l16 & 1)*4] = pk;
            }
        } else {
            #pragma unroll
            for (int r = 0; r < 4; r++) {
                const int row = quad*4 + r;
                float e[4];
                #pragma unroll
                for (int kf = 0; kf < 4; kf++) {
                    e[kf] = __builtin_amdgcn_exp2f(s[kf][r] * SC);
                    lacc[r] += e[kf];
                }
                uint u01 = __builtin_amdgcn_perm(__builtin_bit_cast(uint, e[1]),
                                                 __builtin_bit_cast(uint, e[0]), 0x07060302u);
                uint u23 = __builtin_amdgcn_perm(__builtin_bit_cast(uint, e[3]),
                                                 __builtin_bit_cast(uint, e[2]), 0x07060302u);
                uint2 pk = {u01, u23};
                int c8 = ((l16 >> 1) ^ (row & 7));
                *(uint2*)&myp[row*64 + c8*8 + (l16 & 1)*4] = pk;
            }
        }
        asm volatile("" ::: "memory");
        bf8 pa[2];
        #pragma unroll
        for (int kc = 0; kc < 2; kc++)
            pa[kc] = *(const bf8*)&myp[l16*64 + (((kc*4 + quad) ^ (l16 & 7)))*8];
        #pragma unroll
        for (int dt = 0; dt < 4; dt++)
            #pragma unroll
            for (int c = 0; c < 2; c++) {
                bf8 vf = *(const bf8*)&Vs[kbase + (c*64 + dt*16)*32];
                o[dt] = __builtin_amdgcn_mfma_f32_16x16x32_bf16(pa[c], vf, o[dt], 0, 0, 0);
            }
        __syncthreads();
        buf ^= 1;
    }
    #pragma unroll
    for (int r = 0; r < 4; r++) {
        float v = lacc[r];
        v += __shfl_xor(v, 1);
        v += __shfl_xor(v, 2);
        v += __shfl_xor(v, 4);
        v += __shfl_xor(v, 8);
        lacc[r] = v;
    }
    const int b = bh >> 4, h = bh & 15;
    #pragma unroll
    for (int r = 0; r < 4; r++) {
        float inv = 1.0f / lacc[r];
        int qi = q0w + quad*4 + r;
        int rowoff = (b*SEQ + qi)*EMB + h*HDIM;
        #pragma unroll
        for (int dt = 0; dt < 4; dt++)
            ctx[rowoff + dt*16 + l16] = f2b(o[dt][r] * inv);
    }
}

// ============================================================================
// Kernel 3: output projection. 64x64 tile, BK=64 (16 iters — half the
// barrier drains of R10's BK=32), 1024 blocks = 4 blocks/CU TLP. No atomics;
// bias in epilogue. (R11 split-K REVERTED: 64MB atomic writes, write-bound.)
// ============================================================================
__global__ __launch_bounds__(256) void gemm_out(
    const short* __restrict__ A, const short* __restrict__ Wb,
    const float* __restrict__ bias, float* __restrict__ out)
{
    __shared__ __align__(16) short As[2*64*32];   // 8KB [kc][row][32sh]
    __shared__ __align__(16) short Bs[2*64*32];   // 8KB
    const int f = blockIdx.x;                   // 0..1023
    const int xcd = f & 7, i = f >> 3;          // i: 0..127
    const int by = xcd*2 + (i & 1);             // 0..15
    const int bx = i >> 1;                      // 0..63
    const int tid  = threadIdx.x;
    const int lane = tid & 63;
    const int w    = tid >> 6;
    const int l16  = lane & 15, quad = lane >> 4;
    const int wm   = (w >> 1) * 32, wn = (w & 1) * 32;
    const int srow = (lane >> 2);
    const int scol = SWZ_SRC(lane);
    f4 acc[2][2] = {};
    for (int k0 = 0; k0 < KTOT; k0 += 64) {
        #pragma unroll
        for (int kc = 0; kc < 2; kc++) {
            int ra = bx*64 + w*16 + srow;
            gl_lds16(&A[(size_t)ra*KTOT + k0 + kc*32 + scol],  &As[kc*2048 + (w*16)*32]);
            int rb = by*64 + w*16 + srow;
            gl_lds16(&Wb[(size_t)rb*KTOT + k0 + kc*32 + scol], &Bs[kc*2048 + (w*16)*32]);
        }
        __syncthreads();
        #pragma unroll
        for (int kc = 0; kc < 2; kc++) {
            bf8 af[2], bf[2];
            #pragma unroll
            for (int t = 0; t < 2; t++) {
                af[t] = *(const bf8*)&As[kc*2048 + (wm + t*16 + l16)*32 + SWZ_RD(quad, l16)];
                bf[t] = *(const bf8*)&Bs[kc*2048 + (wn + t*16 + l16)*32 + SWZ_RD(quad, l16)];
            }
            #pragma unroll
            for (int mt = 0; mt < 2; mt++)
                #pragma unroll
                for (int nt = 0; nt < 2; nt++)
                    acc[mt][nt] = __builtin_amdgcn_mfma_f32_16x16x32_bf16(af[mt], bf[nt], acc[mt][nt], 0, 0, 0);
        }
        __syncthreads();
    }
    #pragma unroll
    for (int mt = 0; mt < 2; mt++)
    #pragma unroll
    for (int nt = 0; nt < 2; nt++) {
        int colg = by*64 + wn + nt*16 + l16;
        float bv = bias[colg];
        #pragma unroll
        for (int r = 0; r < 4; r++) {
            int rowg = bx*64 + wm + mt*16 + quad*4 + r;
            out[(size_t)rowg*EMB + colg] = acc[mt][nt][r] + bv;
        }
    }
}

extern "C" void kernel_launch(void* const* d_in, const int* in_sizes, int n_in,
                              void* d_out, int out_size, void* d_ws, size_t ws_size,
                              hipStream_t stream) {
    const float* X    = (const float*)d_in[0];   // [B,S,E] fp32
    const float* Wqkv = (const float*)d_in[1];   // [3E,E]  fp32
    const float* Bqkv = (const float*)d_in[2];   // [3E]    fp32
    const float* Wout = (const float*)d_in[3];   // [E,E]   fp32
    const float* Bout = (const float*)d_in[4];   // [E]     fp32
    float* out = (float*)d_out;                  // [B,S,E] fp32

    short* xb    = (short*)d_ws;                 // bf16 X      (8 MB)
    short* w1b   = xb  + NX;                     // bf16 Wqkv   (6 MB)
    short* w2b   = w1b + NW1;                    // bf16 Wout   (2 MB)
    short* qb    = w2b + NW2;
    short* kb    = qb  + NX;
    short* vtb   = kb  + NX;
    short* ctx   = vtb + NX;                     // total 48 MB

    cvt_all<<<NCVT/1024, 256, 0, stream>>>(X, Wqkv, Wout, xb, w1b, w2b);
    dim3 g1(MTOT/128, 3*EMB/64);                 // 32 x 48
    gemm_qkv<<<g1, 256, 0, stream>>>(xb, w1b, Bqkv, qb, kb, vtb);
    attn<<<dim3(1024), 256, 0, stream>>>(qb, kb, vtb, ctx);
    gemm_out<<<dim3(1024), 256, 0, stream>>>(ctx, w2b, Bout, out);
}

// Round 13
// 177.372 us; speedup vs baseline: 1.2619x; 1.0391x over previous
//
#include <hip/hip_runtime.h>
#include <hip/hip_bf16.h>

// ---- problem constants ----
#define BATCH 2
#define SEQ   2048
#define EMB   1024
#define NHEAD 16
#define HDIM  64
#define MTOT  (BATCH*SEQ)     // 4096
#define KTOT  EMB             // 1024

#define NX  (MTOT*EMB)        // 4,194,304  X elems
#define NW1 (3*EMB*EMB)       // 3,145,728  Wqkv elems
#define NW2 (EMB*EMB)         // 1,048,576  Wout elems
#define NCVT (NX+NW1+NW2)

typedef short bf8 __attribute__((ext_vector_type(8)));   // 8 bf16 (4 VGPRs) MFMA A/B frag
typedef short s4v __attribute__((ext_vector_type(4)));   // 4 bf16, 8B
typedef float f4  __attribute__((ext_vector_type(4)));   // MFMA C/D frag
typedef unsigned int uint;

__device__ __forceinline__ short f2b(float f) {
    __hip_bfloat16 h = __float2bfloat16(f);
    return __builtin_bit_cast(short, h);
}
// async global->LDS, 16B per lane; lds dest = wave-uniform base + lane*16
__device__ __forceinline__ void gl_lds16(const short* g, short* l) {
    __builtin_amdgcn_global_load_lds(
        (const __attribute__((address_space(1))) uint*)g,
        (__attribute__((address_space(3))) uint*)l, 16, 0, 0);
}
// 64B-row LDS tiles: bank swizzle (store global chunk c^f(r) at LDS chunk c).
#define SWZ_SRC(lane)      ((((lane) ^ ((lane)>>2) ^ ((lane)>>4)) & 3) * 8)
#define SWZ_RD(quad, l16)  ((((quad) ^ (l16) ^ ((l16)>>2)) & 3) * 8)

// ============================================================================
// Kernel 0: fp32 -> bf16 convert (X, Wqkv, Wout). Coalesced float4 -> bf16x4.
// ============================================================================
__global__ __launch_bounds__(256) void cvt_all(
    const float* __restrict__ X, const float* __restrict__ W1,
    const float* __restrict__ W2,
    short* __restrict__ xb, short* __restrict__ w1b, short* __restrict__ w2b)
{
    int i4 = (blockIdx.x * 256 + threadIdx.x) * 4;
    const float* src; short* dst; int off;
    if (i4 < NX)            { src = X;  dst = xb;  off = i4; }
    else if (i4 < NX + NW1) { src = W1; dst = w1b; off = i4 - NX; }
    else                    { src = W2; dst = w2b; off = i4 - NX - NW1; }
    float4 v = *(const float4*)&src[off];
    s4v o; o[0]=f2b(v.x); o[1]=f2b(v.y); o[2]=f2b(v.z); o[3]=f2b(v.w);
    *(s4v*)&dst[off] = o;
}

// ============================================================================
// Kernel 1: QKV projection — R10-exact best form: 128x128 tile, BK=64
// (16 K-iters), single-buffer DMA staging, plain 2-D grid 32x24 = 768 blocks.
// (R11/R12's 128x64 REVERTED: 1.5x staging bytes/FLOP -> 53 vs 45.7 µs.)
// XOR bank swizzle. Scatter epilogue: Q,K [B,H,S,D]; V^T key-swizzled.
// ============================================================================
__global__ __launch_bounds__(256) void gemm_qkv(
    const short* __restrict__ Xb, const short* __restrict__ Wb,
    const float* __restrict__ bias,
    short* __restrict__ qb, short* __restrict__ kb, short* __restrict__ vtb)
{
    __shared__ __align__(16) short As[2*128*32];   // 16KB [kc][row][32sh]
    __shared__ __align__(16) short Bs[2*128*32];   // 16KB
    const int tid  = threadIdx.x;
    const int lane = tid & 63;
    const int w    = tid >> 6;
    const int l16  = lane & 15, quad = lane >> 4;
    const int wm   = (w >> 1) * 64, wn = (w & 1) * 64;
    const int srow = (lane >> 2);
    const int scol = SWZ_SRC(lane);
    f4 acc[4][4] = {};
    for (int k0 = 0; k0 < KTOT; k0 += 64) {
        #pragma unroll
        for (int t = 0; t < 4; t++) {
            const int rr = w*32 + (t & 1)*16;
            const int kc = t >> 1;
            int ra = blockIdx.x*128 + rr + srow;
            gl_lds16(&Xb[(size_t)ra*KTOT + k0 + kc*32 + scol], &As[kc*4096 + rr*32]);
            int rb = blockIdx.y*128 + rr + srow;
            gl_lds16(&Wb[(size_t)rb*KTOT + k0 + kc*32 + scol], &Bs[kc*4096 + rr*32]);
        }
        __syncthreads();
        #pragma unroll
        for (int kc = 0; kc < 2; kc++) {
            bf8 af[4], bf[4];
            #pragma unroll
            for (int t = 0; t < 4; t++) {
                af[t] = *(const bf8*)&As[kc*4096 + (wm + t*16 + l16)*32 + SWZ_RD(quad, l16)];
                bf[t] = *(const bf8*)&Bs[kc*4096 + (wn + t*16 + l16)*32 + SWZ_RD(quad, l16)];
            }
            #pragma unroll
            for (int mt = 0; mt < 4; mt++)
                #pragma unroll
                for (int nt = 0; nt < 4; nt++)
                    acc[mt][nt] = __builtin_amdgcn_mfma_f32_16x16x32_bf16(af[mt], bf[nt], acc[mt][nt], 0, 0, 0);
        }
        __syncthreads();
    }
    #pragma unroll
    for (int mt = 0; mt < 4; mt++)
    #pragma unroll
    for (int nt = 0; nt < 4; nt++) {
        int colg = blockIdx.y*128 + wn + nt*16 + l16;
        float bv = bias[colg];
        #pragma unroll
        for (int r = 0; r < 4; r++) {
            int rowg = blockIdx.x*128 + wm + mt*16 + quad*4 + r;
            short h = f2b(acc[mt][nt][r] + bv);
            int bb = rowg >> 11, s = rowg & 2047;
            if (colg < 1024) {
                int hh = colg >> 6, d = colg & 63;
                qb[(((bb*NHEAD + hh)*SEQ + s) << 6) + d] = h;
            } else if (colg < 2048) {
                int c2 = colg - 1024, hh = c2 >> 6, d = c2 & 63;
                kb[(((bb*NHEAD + hh)*SEQ + s) << 6) + d] = h;
            } else {
                int c3 = colg - 2048, hh = c3 >> 6, d = c3 & 63;
                int ssw = (s & ~63) | (((s & 15) << 2) | ((s >> 4) & 3));
                vtb[((bb*NHEAD + hh)*HDIM + d)*SEQ + ssw] = h;
            }
        }
    }
}

// ============================================================================
// Kernel 2: causal flash attention (unchanged from R10). Balanced map: CU
// slot gets 4 tiles of the SAME head, tq in {j,15-j,16+j,31-j}. LDS K/V dbuf
// DMA; masked stage peeled; no-max softmax; exp2; v_perm pack.
// ============================================================================
__global__ __launch_bounds__(256, 4) void attn(
    const short* __restrict__ qb, const short* __restrict__ kb,
    const short* __restrict__ vtb, short* __restrict__ ctx)
{
    __shared__ __align__(16) short Ks[2*4096];      // 16KB [buf][c][key][32sh]
    __shared__ __align__(16) short Vs[2*4096];      // 16KB
    __shared__ __align__(16) short pl[4][16*64];    //  8KB
    const int tid = threadIdx.x;
    const int w = tid >> 6, lane = tid & 63;
    const int l16 = lane & 15, quad = lane >> 4;
    const int f  = blockIdx.x;                      // 0..1023
    const int bh = f & 31;
    const int j5 = (f >> 5) & 7;
    const int hq = f >> 8;                          // 0..3
    const int tq = (hq == 0) ? j5 : (hq == 1) ? (15 - j5)
                 : (hq == 2) ? (16 + j5) : (31 - j5);
    const int q0w = tq*64 + w*16;
    const int base = bh * (SEQ*HDIM);
    short* myp = pl[w];
    const float SC = 0.125f * 1.44269504f;          // 1/sqrt(64) * log2(e)

    const int lq  = lane >> 2;
    const int lsw = SWZ_SRC(lane);

    const bool isk = (w < 2);
    short* tb = isk ? Ks : Vs;
    const int sstep = isk ? 64*HDIM : 64;
    const short* sp0; const short* sp1; const short* sp2; const short* sp3;
    int dof[4];
    {
        const int wb2 = (w & 1) * 4;
        #pragma unroll
        for (int tt = 0; tt < 4; tt++) {
            int t = wb2 + tt, cc = t & 1, g = (t >> 1) & 3;
            dof[tt] = (cc*64 + g*16)*32;
            const short* s = isk ? &kb[base + (g*16 + lq)*HDIM + cc*32 + lsw]
                                 : &vtb[base + (g*16 + lq)*SEQ + cc*32 + lsw];
            if (tt == 0) sp0 = s; else if (tt == 1) sp1 = s;
            else if (tt == 2) sp2 = s; else sp3 = s;
        }
    }

    bf8 qa[2];
    #pragma unroll
    for (int kc = 0; kc < 2; kc++)
        qa[kc] = *(const bf8*)&qb[base + (q0w + l16)*HDIM + kc*32 + quad*8];

    f4 o[4] = {};
    float lacc[4] = {};
    const int rdK = l16*32 + SWZ_RD(quad, l16);

    gl_lds16(sp0, tb + dof[0]); gl_lds16(sp1, tb + dof[1]);
    gl_lds16(sp2, tb + dof[2]); gl_lds16(sp3, tb + dof[3]);
    sp0 += sstep; sp1 += sstep; sp2 += sstep; sp3 += sstep;
    __syncthreads();

    int buf = 0;
    for (int st = 0; st <= tq; st++) {
        if (st < tq) {
            short* d = tb + (buf ^ 1)*4096;
            gl_lds16(sp0, d + dof[0]); gl_lds16(sp1, d + dof[1]);
            gl_lds16(sp2, d + dof[2]); gl_lds16(sp3, d + dof[3]);
            sp0 += sstep; sp1 += sstep; sp2 += sstep; sp3 += sstep;
        }
        const int kbase = buf*4096 + rdK;
        f4 s[4] = {};
        #pragma unroll
        for (int kf = 0; kf < 4; kf++)
            #pragma unroll
            for (int c = 0; c < 2; c++) {
                bf8 kfr = *(const bf8*)&Ks[kbase + (c*64 + kf*16)*32];
                s[kf] = __builtin_amdgcn_mfma_f32_16x16x32_bf16(qa[c], kfr, s[kf], 0, 0, 0);
            }
        if (st == tq) {
            const int j0 = st*64;
            #pragma unroll
            for (int r = 0; r < 4; r++) {
                const int row = quad*4 + r;
                const int qi  = q0w + row;
                float e[4];
                #pragma unroll
                for (int kf = 0; kf < 4; kf++) {
                    e[kf] = __builtin_amdgcn_exp2f(s[kf][r] * SC);
                    if (j0 + kf*16 + l16 > qi) e[kf] = 0.0f;
                    lacc[r] += e[kf];
                }
                uint u01 = __builtin_amdgcn_perm(__builtin_bit_cast(uint, e[1]),
                                                 __builtin_bit_cast(uint, e[0]), 0x07060302u);
                uint u23 = __builtin_amdgcn_perm(__builtin_bit_cast(uint, e[3]),
                                                 __builtin_bit_cast(uint, e[2]), 0x07060302u);
                uint2 pk = {u01, u23};
                int c8 = ((l16 >> 1) ^ (row & 7));
                *(uint2*)&myp[row*64 + c8*8 + (l16 & 1)*4] = pk;
            }
        } else {
            #pragma unroll
            for (int r = 0; r < 4; r++) {
                const int row = quad*4 + r;
                float e[4];
                #pragma unroll
                for (int kf = 0; kf < 4; kf++) {
                    e[kf] = __builtin_amdgcn_exp2f(s[kf][r] * SC);
                    lacc[r] += e[kf];
                }
                uint u01 = __builtin_amdgcn_perm(__builtin_bit_cast(uint, e[1]),
                                                 __builtin_bit_cast(uint, e[0]), 0x07060302u);
                uint u23 = __builtin_amdgcn_perm(__builtin_bit_cast(uint, e[3]),
                                                 __builtin_bit_cast(uint, e[2]), 0x07060302u);
                uint2 pk = {u01, u23};
                int c8 = ((l16 >> 1) ^ (row & 7));
                *(uint2*)&myp[row*64 + c8*8 + (l16 & 1)*4] = pk;
            }
        }
        asm volatile("" ::: "memory");
        bf8 pa[2];
        #pragma unroll
        for (int kc = 0; kc < 2; kc++)
            pa[kc] = *(const bf8*)&myp[l16*64 + (((kc*4 + quad) ^ (l16 & 7)))*8];
        #pragma unroll
        for (int dt = 0; dt < 4; dt++)
            #pragma unroll
            for (int c = 0; c < 2; c++) {
                bf8 vf = *(const bf8*)&Vs[kbase + (c*64 + dt*16)*32];
                o[dt] = __builtin_amdgcn_mfma_f32_16x16x32_bf16(pa[c], vf, o[dt], 0, 0, 0);
            }
        __syncthreads();
        buf ^= 1;
    }
    #pragma unroll
    for (int r = 0; r < 4; r++) {
        float v = lacc[r];
        v += __shfl_xor(v, 1);
        v += __shfl_xor(v, 2);
        v += __shfl_xor(v, 4);
        v += __shfl_xor(v, 8);
        lacc[r] = v;
    }
    const int b = bh >> 4, h = bh & 15;
    #pragma unroll
    for (int r = 0; r < 4; r++) {
        float inv = 1.0f / lacc[r];
        int qi = q0w + quad*4 + r;
        int rowoff = (b*SEQ + qi)*EMB + h*HDIM;
        #pragma unroll
        for (int dt = 0; dt < 4; dt++)
            ctx[rowoff + dt*16 + l16] = f2b(o[dt][r] * inv);
    }
}

// ============================================================================
// Kernel 3: output projection (unchanged from R12). 64x64 tile, BK=64,
// 1024 blocks = 4 blocks/CU TLP. Bias in epilogue, plain stores.
// ============================================================================
__global__ __launch_bounds__(256) void gemm_out(
    const short* __restrict__ A, const short* __restrict__ Wb,
    const float* __restrict__ bias, float* __restrict__ out)
{
    __shared__ __align__(16) short As[2*64*32];   // 8KB [kc][row][32sh]
    __shared__ __align__(16) short Bs[2*64*32];   // 8KB
    const int f = blockIdx.x;                   // 0..1023
    const int xcd = f & 7, i = f >> 3;          // i: 0..127
    const int by = xcd*2 + (i & 1);             // 0..15
    const int bx = i >> 1;                      // 0..63
    const int tid  = threadIdx.x;
    const int lane = tid & 63;
    const int w    = tid >> 6;
    const int l16  = lane & 15, quad = lane >> 4;
    const int wm   = (w >> 1) * 32, wn = (w & 1) * 32;
    const int srow = (lane >> 2);
    const int scol = SWZ_SRC(lane);
    f4 acc[2][2] = {};
    for (int k0 = 0; k0 < KTOT; k0 += 64) {
        #pragma unroll
        for (int kc = 0; kc < 2; kc++) {
            int ra = bx*64 + w*16 + srow;
            gl_lds16(&A[(size_t)ra*KTOT + k0 + kc*32 + scol],  &As[kc*2048 + (w*16)*32]);
            int rb = by*64 + w*16 + srow;
            gl_lds16(&Wb[(size_t)rb*KTOT + k0 + kc*32 + scol], &Bs[kc*2048 + (w*16)*32]);
        }
        __syncthreads();
        #pragma unroll
        for (int kc = 0; kc < 2; kc++) {
            bf8 af[2], bf[2];
            #pragma unroll
            for (int t = 0; t < 2; t++) {
                af[t] = *(const bf8*)&As[kc*2048 + (wm + t*16 + l16)*32 + SWZ_RD(quad, l16)];
                bf[t] = *(const bf8*)&Bs[kc*2048 + (wn + t*16 + l16)*32 + SWZ_RD(quad, l16)];
            }
            #pragma unroll
            for (int mt = 0; mt < 2; mt++)
                #pragma unroll
                for (int nt = 0; nt < 2; nt++)
                    acc[mt][nt] = __builtin_amdgcn_mfma_f32_16x16x32_bf16(af[mt], bf[nt], acc[mt][nt], 0, 0, 0);
        }
        __syncthreads();
    }
    #pragma unroll
    for (int mt = 0; mt < 2; mt++)
    #pragma unroll
    for (int nt = 0; nt < 2; nt++) {
        int colg = by*64 + wn + nt*16 + l16;
        float bv = bias[colg];
        #pragma unroll
        for (int r = 0; r < 4; r++) {
            int rowg = bx*64 + wm + mt*16 + quad*4 + r;
            out[(size_t)rowg*EMB + colg] = acc[mt][nt][r] + bv;
        }
    }
}

extern "C" void kernel_launch(void* const* d_in, const int* in_sizes, int n_in,
                              void* d_out, int out_size, void* d_ws, size_t ws_size,
                              hipStream_t stream) {
    const float* X    = (const float*)d_in[0];   // [B,S,E] fp32
    const float* Wqkv = (const float*)d_in[1];   // [3E,E]  fp32
    const float* Bqkv = (const float*)d_in[2];   // [3E]    fp32
    const float* Wout = (const float*)d_in[3];   // [E,E]   fp32
    const float* Bout = (const float*)d_in[4];   // [E]     fp32
    float* out = (float*)d_out;                  // [B,S,E] fp32

    short* xb    = (short*)d_ws;                 // bf16 X      (8 MB)
    short* w1b   = xb  + NX;                     // bf16 Wqkv   (6 MB)
    short* w2b   = w1b + NW1;                    // bf16 Wout   (2 MB)
    short* qb    = w2b + NW2;
    short* kb    = qb  + NX;
    short* vtb   = kb  + NX;
    short* ctx   = vtb + NX;                     // total 48 MB

    cvt_all<<<NCVT/1024, 256, 0, stream>>>(X, Wqkv, Wout, xb, w1b, w2b);
    dim3 g1(MTOT/128, 3*EMB/128);                // 32 x 24
    gemm_qkv<<<g1, 256, 0, stream>>>(xb, w1b, Bqkv, qb, kb, vtb);
    attn<<<dim3(1024), 256, 0, stream>>>(qb, kb, vtb, ctx);
    gemm_out<<<dim3(1024), 256, 0, stream>>>(ctx, w2b, Bout, out);
}